// Round 3
// baseline (1187.941 us; speedup 1.0000x reference)
//
#include <hip/hip_runtime.h>
#include <hip/hip_bf16.h>

typedef __bf16 bf16;
typedef __bf16 bf16x8 __attribute__((ext_vector_type(8)));
typedef float f32x4 __attribute__((ext_vector_type(4)));

#define QSCALE 0.18033688011112042f  /* (1/8) * log2(e) : folds softmax scale into Wq */

// raw v_exp_f32 (exp2). Inputs here are |x| <~ 2.5 so no edge-case handling needed.
#define EXP2(x) __builtin_amdgcn_exp2f(x)

// ---- async global->LDS (16B per lane, wave-uniform LDS base + lane*16) ----
__device__ __forceinline__ void load_lds16(const void* gp, void* lp) {
  __builtin_amdgcn_global_load_lds((const __attribute__((address_space(1))) void*)gp,
                                   (__attribute__((address_space(3))) void*)lp, 16, 0, 0);
}

// ---------------------------------------------------------------------------
// Kernel T: x [B,C,N] fp32 -> t [B,N,C] bf16   (B=32, C=640, N=1024)
// ---------------------------------------------------------------------------
__global__ __launch_bounds__(256) void k_transpose(const float* __restrict__ x,
                                                   bf16* __restrict__ t) {
  __shared__ float tile[64][65];
  const int b = blockIdx.z, c0 = blockIdx.y * 64, n0 = blockIdx.x * 64;
  const int tid = threadIdx.x, lx = tid & 63, ly = tid >> 6;
  const float* xp = x + ((size_t)b * 640 + c0) * 1024 + n0;
#pragma unroll
  for (int i = 0; i < 16; ++i) {
    int c = i * 4 + ly;
    tile[c][lx] = xp[(size_t)c * 1024 + lx];
  }
  __syncthreads();
  bf16* tp = t + ((size_t)b * 1024 + n0) * 640 + c0;
#pragma unroll
  for (int i = 0; i < 16; ++i) {
    int n = i * 4 + ly;
    tp[(size_t)n * 640 + lx] = (bf16)tile[lx][n];
  }
}

// ---------------------------------------------------------------------------
// Kernel Wc: cast all three weight matrices fp32 -> bf16 (Wq pre-scaled)
// ---------------------------------------------------------------------------
__global__ __launch_bounds__(256) void k_castw3(const float* __restrict__ wq,
                                                const float* __restrict__ wk,
                                                const float* __restrict__ wv,
                                                bf16* __restrict__ dst) {
  int i = blockIdx.x * 256 + threadIdx.x;
  if (i < 655360) dst[i] = (bf16)(wq[i] * QSCALE);
  else if (i < 1310720) dst[i] = (bf16)wk[i - 655360];
  else if (i < 1966080) dst[i] = (bf16)wv[i - 1310720];
}

// ---------------------------------------------------------------------------
// Kernel P: C[32768 x 3072] = A[32768 x 640] * B[3072 x 640]^T  (bf16 in/out)
// 128x128 tile, BK=64, 4 waves (2x2), 16x16x32 MFMA.
// R7: single-barrier async double-buffer (R6-proven shape): barrier drains
// stage(kt) issued one full compute earlier -> cheap; stage(kt+1) overlaps
// compute(kt). Epilogue transposes through LDS -> bf16x8 (16 B) stores.
// ---------------------------------------------------------------------------
__global__ __launch_bounds__(256) void k_gemm_qkv(const bf16* __restrict__ A,
                                                  const bf16* __restrict__ Bw,
                                                  bf16* __restrict__ qkv) {
  __shared__ __align__(16) bf16 smem[2][2][8192];   // [buf][A/B][128*64] = 64 KB
  const int tid = threadIdx.x;
  const int lane = tid & 63;
  const int w = tid >> 6;
  const int wm = w & 1, wn = w >> 1;
  const int g = lane >> 4, ln = lane & 15;
  const int m0 = blockIdx.x * 128;
  const int n0 = blockIdx.y * 128;

  f32x4 acc[4][4];
#pragma unroll
  for (int i = 0; i < 4; ++i)
#pragma unroll
    for (int j = 0; j < 4; ++j)
#pragma unroll
      for (int r = 0; r < 4; ++r) acc[i][j][r] = 0.f;

  // stage A+B K-tile kt into smem[buf]: chunk c holds (m=c>>3, kq=(c&7)^(m&7))
#define GSTAGE(buf, kt)                                                        \
  do {                                                                         \
    _Pragma("unroll") for (int it_ = 0; it_ < 4; ++it_) {                      \
      int c_ = it_ * 256 + w * 64 + lane;                                      \
      int m_ = c_ >> 3;                                                        \
      int kq_ = (c_ & 7) ^ (m_ & 7);                                           \
      load_lds16(A + (size_t)(m0 + m_) * 640 + ((kt) * 64 + kq_ * 8),          \
                 &smem[buf][0][(size_t)(it_ * 256 + w * 64) * 8]);             \
      load_lds16(Bw + (size_t)(n0 + m_) * 640 + ((kt) * 64 + kq_ * 8),        \
                 &smem[buf][1][(size_t)(it_ * 256 + w * 64) * 8]);             \
    }                                                                          \
  } while (0)

  GSTAGE(0, 0);
  for (int kt = 0; kt < 10; ++kt) {
    const int cur = kt & 1;
    __syncthreads();                    // drains stage(kt); buffer handoff
    if (kt + 1 < 10) GSTAGE(1 - cur, kt + 1);
    const bf16* As = smem[cur][0];
    const bf16* Bs = smem[cur][1];
#pragma unroll
    for (int kk = 0; kk < 2; ++kk) {
      bf16x8 af[4], bfr[4];
#pragma unroll
      for (int mi = 0; mi < 4; ++mi) {
        int m = wm * 64 + mi * 16 + ln;
        int cc = m * 8 + ((kk * 4 + g) ^ (m & 7));
        af[mi] = *(const bf16x8*)(As + cc * 8);
      }
#pragma unroll
      for (int ni = 0; ni < 4; ++ni) {
        int n = wn * 64 + ni * 16 + ln;
        int cc = n * 8 + ((kk * 4 + g) ^ (n & 7));
        bfr[ni] = *(const bf16x8*)(Bs + cc * 8);
      }
#pragma unroll
      for (int mi = 0; mi < 4; ++mi)
#pragma unroll
        for (int ni = 0; ni < 4; ++ni)
          acc[mi][ni] = __builtin_amdgcn_mfma_f32_16x16x32_bf16(af[mi], bfr[ni], acc[mi][ni], 0, 0, 0);
    }
  }
#undef GSTAGE

  // ---- epilogue: transpose through LDS, then 16 B stores ----
  __syncthreads();                       // all compute done; smem reusable
  bf16* ct = &smem[0][0][0];             // 32768 bf16 avail; stride 136 (pad)
#pragma unroll
  for (int mi = 0; mi < 4; ++mi)
#pragma unroll
    for (int ni = 0; ni < 4; ++ni)
#pragma unroll
      for (int r = 0; r < 4; ++r) {
        int row = wm * 64 + mi * 16 + g * 4 + r;
        int col = wn * 64 + ni * 16 + ln;
        ct[row * 136 + col] = (bf16)acc[mi][ni][r];
      }
  __syncthreads();
  const int which = n0 >> 10;
  const int hbase = (n0 >> 6) & 15;
#pragma unroll
  for (int p = 0; p < 8; ++p) {
    int row = p * 16 + (tid >> 4);       // tile row 0..127
    int chunk = tid & 15;                // 16 chunks of 8 cols
    bf16x8 vv = *(const bf16x8*)(ct + row * 136 + chunk * 8);
    int gr = m0 + row;
    int bb = gr >> 10, n = gr & 1023;
    int h = hbase + (chunk >> 3);
    int d0 = (chunk & 7) * 8;
    *(bf16x8*)(qkv + (size_t)which * 33554432 +
               (((size_t)bb * 16 + h) * 1024 + n) * 64 + d0) = vv;
  }
}

// ---------------------------------------------------------------------------
// Kernel A: fused attention column-weights, single-MFMA-pass + fp8 replay.
// R9: R8's 32-row/wave cache (es[16][2][4] = 128 VGPR) spilled to scratch
// (WRITE_SIZE 1.24 GB, 760 us). Halve it: 16 rows/wave, es[16][4] = 64 VGPR
// -> total live ~120, spill-free. Block = 4 waves = 64 rows; grid 8192.
// Pass 1 (MFMA+exp2, fp8-pack into regs) + barrier-free register replay.
// fp8 e4m3 rounding of exp2(s) validated on HW: absmax identical to exact.
// XCD swizzle: all 16 i-tiles of a bh share idx%8 -> K stays L2-hot.
// ---------------------------------------------------------------------------
__global__ __launch_bounds__(256, 2) void k_attn(const bf16* __restrict__ q,
                                                 const bf16* __restrict__ kmat,
                                                 float* __restrict__ wsum) {
  __shared__ __align__(16) bf16 Ks[2][4096];   // 2 x 64x64 bf16 = 16 KB
  const int idx = blockIdx.x;
  const int xcd = idx & 7;
  const int y = idx >> 3;
  const int it = y & 15;
  const int bh = xcd + ((y >> 4) << 3);   // 16 i-tiles of bh share idx%8
  const int tid = threadIdx.x;
  const int lane = tid & 63;
  const int w = tid >> 6;
  const int g = lane >> 4, ln = lane & 15;
  const bf16* qb = q + (size_t)bh * 65536;
  const bf16* kb = kmat + (size_t)bh * 65536;
  const int i0 = it * 64 + w * 16;        // 16 rows per wave

  const f32x4 zf = {0.f, 0.f, 0.f, 0.f};

#define STAGEK(buf, jt)                                                       \
  do {                                                                        \
    _Pragma("unroll") for (int call_ = 0; call_ < 2; ++call_) {               \
      int p_ = w * 128 + call_ * 64 + lane;                                   \
      int j_ = p_ >> 3;                                                       \
      int kq_ = (p_ & 7) ^ (j_ & 7);                                          \
      load_lds16(kb + (size_t)((jt) * 64 + j_) * 64 + kq_ * 8,                \
                 &Ks[buf][(size_t)(w * 128 + call_ * 64) * 8]);               \
    }                                                                         \
  } while (0)

#define KFRAG(buf, ni, kc)                                                    \
  (*(const bf16x8*)(&Ks[buf][(size_t)(((ni) * 16 + ln) * 8 +                  \
                                      (((kc) * 4 + g) ^ (ln & 7))) * 8]))

  // Q fragments: A-layout m=lane&15, k=(lane>>4)*8+j ; 1 m-tile, regs only
  bf16x8 qf[2];
#pragma unroll
  for (int kc = 0; kc < 2; ++kc)
    qf[kc] = *(const bf16x8*)(qb + (size_t)(i0 + ln) * 64 + kc * 32 + g * 8);

  float rs[4] = {0.f, 0.f, 0.f, 0.f};
  unsigned es[16][4];                     // fp8x4-packed exp2(s): 64 VGPRs

  // ---- single MFMA+exp pass: row sums + fp8 score cache ----
  STAGEK(0, 0);
#pragma unroll
  for (int jt = 0; jt < 16; ++jt) {
    const int cur = jt & 1;
    __syncthreads();                      // drains stage(jt); buffer handoff
    if (jt + 1 < 16) STAGEK(1 - cur, jt + 1);
#pragma unroll
    for (int ni = 0; ni < 4; ++ni) {
      bf16x8 k0 = KFRAG(cur, ni, 0);
      bf16x8 k1 = KFRAG(cur, ni, 1);
      f32x4 s = __builtin_amdgcn_mfma_f32_16x16x32_bf16(qf[0], k0, zf, 0, 0, 0);
      s = __builtin_amdgcn_mfma_f32_16x16x32_bf16(qf[1], k1, s, 0, 0, 0);
      float e0 = EXP2(s[0]), e1 = EXP2(s[1]), e2 = EXP2(s[2]), e3 = EXP2(s[3]);
      rs[0] += e0; rs[1] += e1; rs[2] += e2; rs[3] += e3;
      int p = __builtin_amdgcn_cvt_pk_fp8_f32(e0, e1, 0, false);
      p = __builtin_amdgcn_cvt_pk_fp8_f32(e2, e3, p, true);
      es[jt][ni] = (unsigned)p;
    }
  }
  // reduce row sums across the 16 lanes sharing g (cols live in lane&15)
  float rinv[4];
#pragma unroll
  for (int r = 0; r < 4; ++r) {
    float v = rs[r];
    v += __shfl_xor(v, 1);
    v += __shfl_xor(v, 2);
    v += __shfl_xor(v, 4);
    v += __shfl_xor(v, 8);
    rinv[r] = 1.0f / v;
  }

  // ---- replay pass: barrier-free, register-only column accumulation ----
#pragma unroll
  for (int jt = 0; jt < 16; ++jt) {
#pragma unroll
    for (int ni = 0; ni < 4; ++ni) {
      const unsigned E = es[jt][ni];
      float cs = __builtin_amdgcn_cvt_f32_fp8(E, 0) * rinv[0];
      cs += __builtin_amdgcn_cvt_f32_fp8(E, 1) * rinv[1];
      cs += __builtin_amdgcn_cvt_f32_fp8(E, 2) * rinv[2];
      cs += __builtin_amdgcn_cvt_f32_fp8(E, 3) * rinv[3];
      cs += __shfl_xor(cs, 16);
      cs += __shfl_xor(cs, 32);
      if (g == 0) atomicAdd(wsum + (size_t)bh * 1024 + jt * 64 + ni * 16 + ln, cs);
    }
  }
#undef STAGEK
#undef KFRAG
}

// ---------------------------------------------------------------------------
// Kernel F: out[bh][d] = LN_d( (1/N) * sum_j w[bh][j] * V[bh][j][d] )
// ---------------------------------------------------------------------------
__global__ __launch_bounds__(256) void k_final(const float* __restrict__ wsum,
                                               const bf16* __restrict__ v,
                                               const float* __restrict__ gamma,
                                               const float* __restrict__ beta,
                                               float* __restrict__ out) {
  const int bh = blockIdx.x;
  const int tid = threadIdx.x;
  const int d = tid & 63, part = tid >> 6;
  const bf16* vb = v + (size_t)bh * 65536;
  const float* wb = wsum + (size_t)bh * 1024;
  float acc = 0.f;
  for (int j = part * 256; j < part * 256 + 256; ++j)
    acc += wb[j] * (float)vb[(size_t)j * 64 + d];
  __shared__ float red[4][64];
  red[part][d] = acc;
  __syncthreads();
  if (tid < 64) {
    float y = (red[0][d] + red[1][d] + red[2][d] + red[3][d]) * (1.0f / 1024.0f);
    float s1 = y;
#pragma unroll
    for (int off = 1; off < 64; off <<= 1) s1 += __shfl_xor(s1, off);
    float mu = s1 * (1.0f / 64.0f);
    float dy = y - mu;
    float s2 = dy * dy;
#pragma unroll
    for (int off = 1; off < 64; off <<= 1) s2 += __shfl_xor(s2, off);
    float rstd = rsqrtf(s2 * (1.0f / 64.0f) + 1e-5f);
    out[(size_t)bh * 64 + d] = dy * rstd * gamma[d] + beta[d];
  }
}

// ---------------------------------------------------------------------------
extern "C" void kernel_launch(void* const* d_in, const int* in_sizes, int n_in,
                              void* d_out, int out_size, void* d_ws, size_t ws_size,
                              hipStream_t stream) {
  const float* x     = (const float*)d_in[0];
  const float* Wq    = (const float*)d_in[1];
  const float* Wk    = (const float*)d_in[2];
  const float* Wv    = (const float*)d_in[3];
  const float* gamma = (const float*)d_in[4];
  const float* beta  = (const float*)d_in[5];
  float* out = (float*)d_out;

  char* ws = (char*)d_ws;
  bf16*  tbf  = (bf16*)ws;                    // 32768*640*2      = 41,943,040 B
  bf16*  wbf  = (bf16*)(ws + 41943040);       // 3072*640*2       =  3,932,160 B
  bf16*  qkv  = (bf16*)(ws + 45875200);       // 3*512*1024*64*2  = 201,326,592 B
  float* wsum = (float*)(ws + 247201792);     // 512*1024*4       =  2,097,152 B

  (void)hipMemsetAsync(wsum, 0, (size_t)512 * 1024 * sizeof(float), stream);
  k_transpose<<<dim3(16, 10, 32), 256, 0, stream>>>(x, tbf);
  k_castw3<<<7680, 256, 0, stream>>>(Wq, Wk, Wv, wbf);
  k_gemm_qkv<<<dim3(256, 24), 256, 0, stream>>>(tbf, wbf, qkv);
  k_attn<<<8192, 256, 0, stream>>>(qkv, qkv + 33554432, wsum);
  k_final<<<512, 256, 0, stream>>>(wsum, qkv + 67108864, gamma, beta, out);
}

// Round 4
// 711.771 us; speedup vs baseline: 1.6690x; 1.6690x over previous
//
#include <hip/hip_runtime.h>
#include <hip/hip_bf16.h>

typedef __bf16 bf16;
typedef __bf16 bf16x8 __attribute__((ext_vector_type(8)));
typedef float f32x4 __attribute__((ext_vector_type(4)));

#define QSCALE 0.18033688011112042f  /* (1/8) * log2(e) : folds softmax scale into Wq */

// raw v_exp_f32 (exp2). Inputs here are |x| <~ 2.5 so no edge-case handling needed.
#define EXP2(x) __builtin_amdgcn_exp2f(x)

// ---- async global->LDS (16B per lane, wave-uniform LDS base + lane*16) ----
__device__ __forceinline__ void load_lds16(const void* gp, void* lp) {
  __builtin_amdgcn_global_load_lds((const __attribute__((address_space(1))) void*)gp,
                                   (__attribute__((address_space(3))) void*)lp, 16, 0, 0);
}

// ---------------------------------------------------------------------------
// Kernel T: x [B,C,N] fp32 -> t [B,N,C] bf16   (B=32, C=640, N=1024)
// ---------------------------------------------------------------------------
__global__ __launch_bounds__(256) void k_transpose(const float* __restrict__ x,
                                                   bf16* __restrict__ t) {
  __shared__ float tile[64][65];
  const int b = blockIdx.z, c0 = blockIdx.y * 64, n0 = blockIdx.x * 64;
  const int tid = threadIdx.x, lx = tid & 63, ly = tid >> 6;
  const float* xp = x + ((size_t)b * 640 + c0) * 1024 + n0;
#pragma unroll
  for (int i = 0; i < 16; ++i) {
    int c = i * 4 + ly;
    tile[c][lx] = xp[(size_t)c * 1024 + lx];
  }
  __syncthreads();
  bf16* tp = t + ((size_t)b * 1024 + n0) * 640 + c0;
#pragma unroll
  for (int i = 0; i < 16; ++i) {
    int n = i * 4 + ly;
    tp[(size_t)n * 640 + lx] = (bf16)tile[lx][n];
  }
}

// ---------------------------------------------------------------------------
// Kernel Wc: cast all three weight matrices fp32 -> bf16 (Wq pre-scaled)
// ---------------------------------------------------------------------------
__global__ __launch_bounds__(256) void k_castw3(const float* __restrict__ wq,
                                                const float* __restrict__ wk,
                                                const float* __restrict__ wv,
                                                bf16* __restrict__ dst) {
  int i = blockIdx.x * 256 + threadIdx.x;
  if (i < 655360) dst[i] = (bf16)(wq[i] * QSCALE);
  else if (i < 1310720) dst[i] = (bf16)wk[i - 655360];
  else if (i < 1966080) dst[i] = (bf16)wv[i - 1310720];
}

// ---------------------------------------------------------------------------
// Kernel P: C[32768 x 3072] = A[32768 x 640] * B[3072 x 640]^T  (bf16 in/out)
// 128x128 tile, BK=64, 4 waves (2x2), 16x16x32 MFMA.
// R7: single-barrier async double-buffer (R6-proven shape): barrier drains
// stage(kt) issued one full compute earlier -> cheap; stage(kt+1) overlaps
// compute(kt). Epilogue transposes through LDS -> bf16x8 (16 B) stores.
// ---------------------------------------------------------------------------
__global__ __launch_bounds__(256) void k_gemm_qkv(const bf16* __restrict__ A,
                                                  const bf16* __restrict__ Bw,
                                                  bf16* __restrict__ qkv) {
  __shared__ __align__(16) bf16 smem[2][2][8192];   // [buf][A/B][128*64] = 64 KB
  const int tid = threadIdx.x;
  const int lane = tid & 63;
  const int w = tid >> 6;
  const int wm = w & 1, wn = w >> 1;
  const int g = lane >> 4, ln = lane & 15;
  const int m0 = blockIdx.x * 128;
  const int n0 = blockIdx.y * 128;

  f32x4 acc[4][4];
#pragma unroll
  for (int i = 0; i < 4; ++i)
#pragma unroll
    for (int j = 0; j < 4; ++j)
#pragma unroll
      for (int r = 0; r < 4; ++r) acc[i][j][r] = 0.f;

  // stage A+B K-tile kt into smem[buf]: chunk c holds (m=c>>3, kq=(c&7)^(m&7))
#define GSTAGE(buf, kt)                                                        \
  do {                                                                         \
    _Pragma("unroll") for (int it_ = 0; it_ < 4; ++it_) {                      \
      int c_ = it_ * 256 + w * 64 + lane;                                      \
      int m_ = c_ >> 3;                                                        \
      int kq_ = (c_ & 7) ^ (m_ & 7);                                           \
      load_lds16(A + (size_t)(m0 + m_) * 640 + ((kt) * 64 + kq_ * 8),          \
                 &smem[buf][0][(size_t)(it_ * 256 + w * 64) * 8]);             \
      load_lds16(Bw + (size_t)(n0 + m_) * 640 + ((kt) * 64 + kq_ * 8),        \
                 &smem[buf][1][(size_t)(it_ * 256 + w * 64) * 8]);             \
    }                                                                          \
  } while (0)

  GSTAGE(0, 0);
  for (int kt = 0; kt < 10; ++kt) {
    const int cur = kt & 1;
    __syncthreads();                    // drains stage(kt); buffer handoff
    if (kt + 1 < 10) GSTAGE(1 - cur, kt + 1);
    const bf16* As = smem[cur][0];
    const bf16* Bs = smem[cur][1];
#pragma unroll
    for (int kk = 0; kk < 2; ++kk) {
      bf16x8 af[4], bfr[4];
#pragma unroll
      for (int mi = 0; mi < 4; ++mi) {
        int m = wm * 64 + mi * 16 + ln;
        int cc = m * 8 + ((kk * 4 + g) ^ (m & 7));
        af[mi] = *(const bf16x8*)(As + cc * 8);
      }
#pragma unroll
      for (int ni = 0; ni < 4; ++ni) {
        int n = wn * 64 + ni * 16 + ln;
        int cc = n * 8 + ((kk * 4 + g) ^ (n & 7));
        bfr[ni] = *(const bf16x8*)(Bs + cc * 8);
      }
#pragma unroll
      for (int mi = 0; mi < 4; ++mi)
#pragma unroll
        for (int ni = 0; ni < 4; ++ni)
          acc[mi][ni] = __builtin_amdgcn_mfma_f32_16x16x32_bf16(af[mi], bfr[ni], acc[mi][ni], 0, 0, 0);
    }
  }
#undef GSTAGE

  // ---- epilogue: transpose through LDS, then 16 B stores ----
  __syncthreads();                       // all compute done; smem reusable
  bf16* ct = &smem[0][0][0];             // 32768 bf16 avail; stride 136 (pad)
#pragma unroll
  for (int mi = 0; mi < 4; ++mi)
#pragma unroll
    for (int ni = 0; ni < 4; ++ni)
#pragma unroll
      for (int r = 0; r < 4; ++r) {
        int row = wm * 64 + mi * 16 + g * 4 + r;
        int col = wn * 64 + ni * 16 + ln;
        ct[row * 136 + col] = (bf16)acc[mi][ni][r];
      }
  __syncthreads();
  const int which = n0 >> 10;
  const int hbase = (n0 >> 6) & 15;
#pragma unroll
  for (int p = 0; p < 8; ++p) {
    int row = p * 16 + (tid >> 4);       // tile row 0..127
    int chunk = tid & 15;                // 16 chunks of 8 cols
    bf16x8 vv = *(const bf16x8*)(ct + row * 136 + chunk * 8);
    int gr = m0 + row;
    int bb = gr >> 10, n = gr & 1023;
    int h = hbase + (chunk >> 3);
    int d0 = (chunk & 7) * 8;
    *(bf16x8*)(qkv + (size_t)which * 33554432 +
               (((size_t)bb * 16 + h) * 1024 + n) * 64 + d0) = vv;
  }
}

// ---------------------------------------------------------------------------
// Kernel A: fused attention column-weights, single-MFMA-pass + fp8 replay.
// R10: R8/R9 proved the fp8-replay math (absmax identical) but the per-lane
// register score-cache spilled to scratch both times (WRITE_SIZE 1.2-1.5 GB).
// Fix: cache lives in LDS. Per wave 16 rows x 1024 cols fp8 = 16 KB ->
// Ps = 64 KB/block + Ks 16 KB = 80 KB -> 2 blocks/CU. Stores/loads are
// wave-private (no barriers in pass 2, no K re-stage, no 2nd MFMA/exp).
// Layout Ps[w][jt][ni][lane]: stride-1 in lane -> 2-way bank alias (free).
// Pass 1: MFMA + exp2 + rowsum + cvt_pk_fp8 -> ds_write_b32.
// Pass 2: ds_read_b32 -> 4x cvt_f32_fp8 * rinv -> shfl reduce -> atomicAdd.
// grid 8192; XCD swizzle: 16 i-tiles of a bh share idx%8 -> K L2-hot.
// ---------------------------------------------------------------------------
__global__ __launch_bounds__(256) void k_attn(const bf16* __restrict__ q,
                                              const bf16* __restrict__ kmat,
                                              float* __restrict__ wsum) {
  __shared__ __align__(16) bf16 Ks[2][4096];   // 2 x 64x64 bf16 = 16 KB
  __shared__ unsigned Ps[4][16][4][64];        // fp8x4 score cache, 64 KB
  const int idx = blockIdx.x;
  const int xcd = idx & 7;
  const int y = idx >> 3;
  const int it = y & 15;
  const int bh = xcd + ((y >> 4) << 3);   // 16 i-tiles of bh share idx%8
  const int tid = threadIdx.x;
  const int lane = tid & 63;
  const int w = tid >> 6;
  const int g = lane >> 4, ln = lane & 15;
  const bf16* qb = q + (size_t)bh * 65536;
  const bf16* kb = kmat + (size_t)bh * 65536;
  const int i0 = it * 64 + w * 16;        // 16 rows per wave

  const f32x4 zf = {0.f, 0.f, 0.f, 0.f};

#define STAGEK(buf, jt)                                                       \
  do {                                                                        \
    _Pragma("unroll") for (int call_ = 0; call_ < 2; ++call_) {               \
      int p_ = w * 128 + call_ * 64 + lane;                                   \
      int j_ = p_ >> 3;                                                       \
      int kq_ = (p_ & 7) ^ (j_ & 7);                                          \
      load_lds16(kb + (size_t)((jt) * 64 + j_) * 64 + kq_ * 8,                \
                 &Ks[buf][(size_t)(w * 128 + call_ * 64) * 8]);               \
    }                                                                         \
  } while (0)

#define KFRAG(buf, ni, kc)                                                    \
  (*(const bf16x8*)(&Ks[buf][(size_t)(((ni) * 16 + ln) * 8 +                  \
                                      (((kc) * 4 + g) ^ (ln & 7))) * 8]))

  // Q fragments: A-layout m=lane&15, k=(lane>>4)*8+j ; 1 m-tile, regs only
  bf16x8 qf[2];
#pragma unroll
  for (int kc = 0; kc < 2; ++kc)
    qf[kc] = *(const bf16x8*)(qb + (size_t)(i0 + ln) * 64 + kc * 32 + g * 8);

  float rs[4] = {0.f, 0.f, 0.f, 0.f};

  // ---- pass 1: MFMA + exp2, row sums, fp8 scores -> LDS ----
  STAGEK(0, 0);
  for (int jt = 0; jt < 16; ++jt) {
    const int cur = jt & 1;
    __syncthreads();                      // drains stage(jt); buffer handoff
    if (jt + 1 < 16) STAGEK(1 - cur, jt + 1);
#pragma unroll
    for (int ni = 0; ni < 4; ++ni) {
      bf16x8 k0 = KFRAG(cur, ni, 0);
      bf16x8 k1 = KFRAG(cur, ni, 1);
      f32x4 s = __builtin_amdgcn_mfma_f32_16x16x32_bf16(qf[0], k0, zf, 0, 0, 0);
      s = __builtin_amdgcn_mfma_f32_16x16x32_bf16(qf[1], k1, s, 0, 0, 0);
      float e0 = EXP2(s[0]), e1 = EXP2(s[1]), e2 = EXP2(s[2]), e3 = EXP2(s[3]);
      rs[0] += e0; rs[1] += e1; rs[2] += e2; rs[3] += e3;
      int p = __builtin_amdgcn_cvt_pk_fp8_f32(e0, e1, 0, false);
      p = __builtin_amdgcn_cvt_pk_fp8_f32(e2, e3, p, true);
      Ps[w][jt][ni][lane] = (unsigned)p;
    }
  }
  // reduce row sums across the 16 lanes sharing g (cols live in lane&15)
  float rinv[4];
#pragma unroll
  for (int r = 0; r < 4; ++r) {
    float v = rs[r];
    v += __shfl_xor(v, 1);
    v += __shfl_xor(v, 2);
    v += __shfl_xor(v, 4);
    v += __shfl_xor(v, 8);
    rinv[r] = 1.0f / v;
  }

  // ---- pass 2: wave-private LDS replay (no barriers, no K, no exp) ----
  for (int jt = 0; jt < 16; ++jt) {
#pragma unroll
    for (int ni = 0; ni < 4; ++ni) {
      const unsigned E = Ps[w][jt][ni][lane];
      float cs = __builtin_amdgcn_cvt_f32_fp8(E, 0) * rinv[0];
      cs += __builtin_amdgcn_cvt_f32_fp8(E, 1) * rinv[1];
      cs += __builtin_amdgcn_cvt_f32_fp8(E, 2) * rinv[2];
      cs += __builtin_amdgcn_cvt_f32_fp8(E, 3) * rinv[3];
      cs += __shfl_xor(cs, 16);
      cs += __shfl_xor(cs, 32);
      if (g == 0) atomicAdd(wsum + (size_t)bh * 1024 + jt * 64 + ni * 16 + ln, cs);
    }
  }
#undef STAGEK
#undef KFRAG
}

// ---------------------------------------------------------------------------
// Kernel F: out[bh][d] = LN_d( (1/N) * sum_j w[bh][j] * V[bh][j][d] )
// ---------------------------------------------------------------------------
__global__ __launch_bounds__(256) void k_final(const float* __restrict__ wsum,
                                               const bf16* __restrict__ v,
                                               const float* __restrict__ gamma,
                                               const float* __restrict__ beta,
                                               float* __restrict__ out) {
  const int bh = blockIdx.x;
  const int tid = threadIdx.x;
  const int d = tid & 63, part = tid >> 6;
  const bf16* vb = v + (size_t)bh * 65536;
  const float* wb = wsum + (size_t)bh * 1024;
  float acc = 0.f;
  for (int j = part * 256; j < part * 256 + 256; ++j)
    acc += wb[j] * (float)vb[(size_t)j * 64 + d];
  __shared__ float red[4][64];
  red[part][d] = acc;
  __syncthreads();
  if (tid < 64) {
    float y = (red[0][d] + red[1][d] + red[2][d] + red[3][d]) * (1.0f / 1024.0f);
    float s1 = y;
#pragma unroll
    for (int off = 1; off < 64; off <<= 1) s1 += __shfl_xor(s1, off);
    float mu = s1 * (1.0f / 64.0f);
    float dy = y - mu;
    float s2 = dy * dy;
#pragma unroll
    for (int off = 1; off < 64; off <<= 1) s2 += __shfl_xor(s2, off);
    float rstd = rsqrtf(s2 * (1.0f / 64.0f) + 1e-5f);
    out[(size_t)bh * 64 + d] = dy * rstd * gamma[d] + beta[d];
  }
}

// ---------------------------------------------------------------------------
extern "C" void kernel_launch(void* const* d_in, const int* in_sizes, int n_in,
                              void* d_out, int out_size, void* d_ws, size_t ws_size,
                              hipStream_t stream) {
  const float* x     = (const float*)d_in[0];
  const float* Wq    = (const float*)d_in[1];
  const float* Wk    = (const float*)d_in[2];
  const float* Wv    = (const float*)d_in[3];
  const float* gamma = (const float*)d_in[4];
  const float* beta  = (const float*)d_in[5];
  float* out = (float*)d_out;

  char* ws = (char*)d_ws;
  bf16*  tbf  = (bf16*)ws;                    // 32768*640*2      = 41,943,040 B
  bf16*  wbf  = (bf16*)(ws + 41943040);       // 3072*640*2       =  3,932,160 B
  bf16*  qkv  = (bf16*)(ws + 45875200);       // 3*512*1024*64*2  = 201,326,592 B
  float* wsum = (float*)(ws + 247201792);     // 512*1024*4       =  2,097,152 B

  (void)hipMemsetAsync(wsum, 0, (size_t)512 * 1024 * sizeof(float), stream);
  k_transpose<<<dim3(16, 10, 32), 256, 0, stream>>>(x, tbf);
  k_castw3<<<7680, 256, 0, stream>>>(Wq, Wk, Wv, wbf);
  k_gemm_qkv<<<dim3(256, 24), 256, 0, stream>>>(tbf, wbf, qkv);
  k_attn<<<8192, 256, 0, stream>>>(qkv, qkv + 33554432, wsum);
  k_final<<<512, 256, 0, stream>>>(wsum, qkv + 67108864, gamma, beta, out);
}

// Round 5
// 634.804 us; speedup vs baseline: 1.8714x; 1.1212x over previous
//
#include <hip/hip_runtime.h>
#include <hip/hip_bf16.h>

typedef __bf16 bf16;
typedef __bf16 bf16x8 __attribute__((ext_vector_type(8)));
typedef float f32x4 __attribute__((ext_vector_type(4)));

#define QSCALE 0.18033688011112042f  /* (1/8) * log2(e) : folds softmax scale into Wq */

// raw v_exp_f32 (exp2). Inputs here are |x| <~ 2.5 so no edge-case handling needed.
#define EXP2(x) __builtin_amdgcn_exp2f(x)

// ---- async global->LDS (16B per lane, wave-uniform LDS base + lane*16) ----
__device__ __forceinline__ void load_lds16(const void* gp, void* lp) {
  __builtin_amdgcn_global_load_lds((const __attribute__((address_space(1))) void*)gp,
                                   (__attribute__((address_space(3))) void*)lp, 16, 0, 0);
}

// ---------------------------------------------------------------------------
// Kernel T: x [B,C,N] fp32 -> t [B,N,C] bf16   (B=32, C=640, N=1024)
// ---------------------------------------------------------------------------
__global__ __launch_bounds__(256) void k_transpose(const float* __restrict__ x,
                                                   bf16* __restrict__ t) {
  __shared__ float tile[64][65];
  const int b = blockIdx.z, c0 = blockIdx.y * 64, n0 = blockIdx.x * 64;
  const int tid = threadIdx.x, lx = tid & 63, ly = tid >> 6;
  const float* xp = x + ((size_t)b * 640 + c0) * 1024 + n0;
#pragma unroll
  for (int i = 0; i < 16; ++i) {
    int c = i * 4 + ly;
    tile[c][lx] = xp[(size_t)c * 1024 + lx];
  }
  __syncthreads();
  bf16* tp = t + ((size_t)b * 1024 + n0) * 640 + c0;
#pragma unroll
  for (int i = 0; i < 16; ++i) {
    int n = i * 4 + ly;
    tp[(size_t)n * 640 + lx] = (bf16)tile[lx][n];
  }
}

// ---------------------------------------------------------------------------
// Kernel Wc: cast all three weight matrices fp32 -> bf16 (Wq pre-scaled)
// ---------------------------------------------------------------------------
__global__ __launch_bounds__(256) void k_castw3(const float* __restrict__ wq,
                                                const float* __restrict__ wk,
                                                const float* __restrict__ wv,
                                                bf16* __restrict__ dst) {
  int i = blockIdx.x * 256 + threadIdx.x;
  if (i < 655360) dst[i] = (bf16)(wq[i] * QSCALE);
  else if (i < 1310720) dst[i] = (bf16)wk[i - 655360];
  else if (i < 1966080) dst[i] = (bf16)wv[i - 1310720];
}

// ---------------------------------------------------------------------------
// Kernel P: C[32768 x 3072] = A[32768 x 640] * B[3072 x 640]^T  (bf16 in/out)
// 128x128 tile, BK=64, 4 waves (2x2), 16x16x32 MFMA.
// R7: single-barrier async double-buffer (R6-proven shape): barrier drains
// stage(kt) issued one full compute earlier -> cheap; stage(kt+1) overlaps
// compute(kt). Epilogue transposes through LDS -> bf16x8 (16 B) stores.
// ---------------------------------------------------------------------------
__global__ __launch_bounds__(256) void k_gemm_qkv(const bf16* __restrict__ A,
                                                  const bf16* __restrict__ Bw,
                                                  bf16* __restrict__ qkv) {
  __shared__ __align__(16) bf16 smem[2][2][8192];   // [buf][A/B][128*64] = 64 KB
  const int tid = threadIdx.x;
  const int lane = tid & 63;
  const int w = tid >> 6;
  const int wm = w & 1, wn = w >> 1;
  const int g = lane >> 4, ln = lane & 15;
  const int m0 = blockIdx.x * 128;
  const int n0 = blockIdx.y * 128;

  f32x4 acc[4][4];
#pragma unroll
  for (int i = 0; i < 4; ++i)
#pragma unroll
    for (int j = 0; j < 4; ++j)
#pragma unroll
      for (int r = 0; r < 4; ++r) acc[i][j][r] = 0.f;

  // stage A+B K-tile kt into smem[buf]: chunk c holds (m=c>>3, kq=(c&7)^(m&7))
#define GSTAGE(buf, kt)                                                        \
  do {                                                                         \
    _Pragma("unroll") for (int it_ = 0; it_ < 4; ++it_) {                      \
      int c_ = it_ * 256 + w * 64 + lane;                                      \
      int m_ = c_ >> 3;                                                        \
      int kq_ = (c_ & 7) ^ (m_ & 7);                                           \
      load_lds16(A + (size_t)(m0 + m_) * 640 + ((kt) * 64 + kq_ * 8),          \
                 &smem[buf][0][(size_t)(it_ * 256 + w * 64) * 8]);             \
      load_lds16(Bw + (size_t)(n0 + m_) * 640 + ((kt) * 64 + kq_ * 8),        \
                 &smem[buf][1][(size_t)(it_ * 256 + w * 64) * 8]);             \
    }                                                                          \
  } while (0)

  GSTAGE(0, 0);
  for (int kt = 0; kt < 10; ++kt) {
    const int cur = kt & 1;
    __syncthreads();                    // drains stage(kt); buffer handoff
    if (kt + 1 < 10) GSTAGE(1 - cur, kt + 1);
    const bf16* As = smem[cur][0];
    const bf16* Bs = smem[cur][1];
#pragma unroll
    for (int kk = 0; kk < 2; ++kk) {
      bf16x8 af[4], bfr[4];
#pragma unroll
      for (int mi = 0; mi < 4; ++mi) {
        int m = wm * 64 + mi * 16 + ln;
        int cc = m * 8 + ((kk * 4 + g) ^ (m & 7));
        af[mi] = *(const bf16x8*)(As + cc * 8);
      }
#pragma unroll
      for (int ni = 0; ni < 4; ++ni) {
        int n = wn * 64 + ni * 16 + ln;
        int cc = n * 8 + ((kk * 4 + g) ^ (n & 7));
        bfr[ni] = *(const bf16x8*)(Bs + cc * 8);
      }
#pragma unroll
      for (int mi = 0; mi < 4; ++mi)
#pragma unroll
        for (int ni = 0; ni < 4; ++ni)
          acc[mi][ni] = __builtin_amdgcn_mfma_f32_16x16x32_bf16(af[mi], bfr[ni], acc[mi][ni], 0, 0, 0);
    }
  }
#undef GSTAGE

  // ---- epilogue: transpose through LDS, then 16 B stores ----
  __syncthreads();                       // all compute done; smem reusable
  bf16* ct = &smem[0][0][0];             // 32768 bf16 avail; stride 136 (pad)
#pragma unroll
  for (int mi = 0; mi < 4; ++mi)
#pragma unroll
    for (int ni = 0; ni < 4; ++ni)
#pragma unroll
      for (int r = 0; r < 4; ++r) {
        int row = wm * 64 + mi * 16 + g * 4 + r;
        int col = wn * 64 + ni * 16 + ln;
        ct[row * 136 + col] = (bf16)acc[mi][ni][r];
      }
  __syncthreads();
  const int which = n0 >> 10;
  const int hbase = (n0 >> 6) & 15;
#pragma unroll
  for (int p = 0; p < 8; ++p) {
    int row = p * 16 + (tid >> 4);       // tile row 0..127
    int chunk = tid & 15;                // 16 chunks of 8 cols
    bf16x8 vv = *(const bf16x8*)(ct + row * 136 + chunk * 8);
    int gr = m0 + row;
    int bb = gr >> 10, n = gr & 1023;
    int h = hbase + (chunk >> 3);
    int d0 = (chunk & 7) * 8;
    *(bf16x8*)(qkv + (size_t)which * 33554432 +
               (((size_t)bb * 16 + h) * 1024 + n) * 64 + d0) = vv;
  }
}

// ---------------------------------------------------------------------------
// Kernel A: fused attention column-weights, single-exp pass + fp8 LDS cache.
// R11 post-mortem of R10 (430 us, all pipes idle): (a) v_cvt_f32_fp8 is on
// the slow trans pipe like v_exp (~16cy/wave) so the replay saved no VALU;
// (b) pass 2 was 64 dependent chains of ds_read->cvt->shfl->shfl (>300cy)
// at 2 waves/SIMD -> latency-bound.
// Fixes, keeping the proven pass-1 + 80KB LDS (2 blocks/CU) shape:
//  - int decode: e4m3 byte<<20 reinterpreted f32 == E * 2^-120 EXACTLY
//    (e4m3 = 0eeeemmm, E>0; subnormals too). Fold 2^120 into rinv ->
//    decode = bfe+shl+fma, all full-rate VALU. Zero trans-pipe in pass 2.
//  - column-owner replay: lane L owns output col j=jt*64+L; reads its 4
//    packed words straight from Ps (any lane reads any LDS addr), decodes
//    16 rows vs register rv[16] (rinv broadcast once via 16 shfls),
//    ONE coalesced atomicAdd. No per-iter shfl, no barrier.
//  - Ps XOR swizzle (lane ^ ni*16) -> writes AND column reads 2-way (free).
// ---------------------------------------------------------------------------
__global__ __launch_bounds__(256) void k_attn(const bf16* __restrict__ q,
                                              const bf16* __restrict__ kmat,
                                              float* __restrict__ wsum) {
  __shared__ __align__(16) bf16 Ks[2][4096];   // 2 x 64x64 bf16 = 16 KB
  __shared__ unsigned Ps[4][16][4][64];        // fp8x4 score cache, 64 KB
  const int idx = blockIdx.x;
  const int xcd = idx & 7;
  const int y = idx >> 3;
  const int it = y & 15;
  const int bh = xcd + ((y >> 4) << 3);   // 16 i-tiles of bh share idx%8
  const int tid = threadIdx.x;
  const int lane = tid & 63;
  const int w = tid >> 6;
  const int g = lane >> 4, ln = lane & 15;
  const bf16* qb = q + (size_t)bh * 65536;
  const bf16* kb = kmat + (size_t)bh * 65536;
  const int i0 = it * 64 + w * 16;        // 16 rows per wave

  const f32x4 zf = {0.f, 0.f, 0.f, 0.f};

#define STAGEK(buf, jt)                                                       \
  do {                                                                        \
    _Pragma("unroll") for (int call_ = 0; call_ < 2; ++call_) {               \
      int p_ = w * 128 + call_ * 64 + lane;                                   \
      int j_ = p_ >> 3;                                                       \
      int kq_ = (p_ & 7) ^ (j_ & 7);                                          \
      load_lds16(kb + (size_t)((jt) * 64 + j_) * 64 + kq_ * 8,                \
                 &Ks[buf][(size_t)(w * 128 + call_ * 64) * 8]);               \
    }                                                                         \
  } while (0)

#define KFRAG(buf, ni, kc)                                                    \
  (*(const bf16x8*)(&Ks[buf][(size_t)(((ni) * 16 + ln) * 8 +                  \
                                      (((kc) * 4 + g) ^ (ln & 7))) * 8]))

  // Q fragments: A-layout m=lane&15, k=(lane>>4)*8+j ; 1 m-tile, regs only
  bf16x8 qf[2];
#pragma unroll
  for (int kc = 0; kc < 2; ++kc)
    qf[kc] = *(const bf16x8*)(qb + (size_t)(i0 + ln) * 64 + kc * 32 + g * 8);

  float rs[4] = {0.f, 0.f, 0.f, 0.f};

  // ---- pass 1: MFMA + exp2, row sums, fp8 scores -> LDS (swizzled) ----
  STAGEK(0, 0);
  for (int jt = 0; jt < 16; ++jt) {
    const int cur = jt & 1;
    __syncthreads();                      // drains stage(jt); buffer handoff
    if (jt + 1 < 16) STAGEK(1 - cur, jt + 1);
#pragma unroll
    for (int ni = 0; ni < 4; ++ni) {
      bf16x8 k0 = KFRAG(cur, ni, 0);
      bf16x8 k1 = KFRAG(cur, ni, 1);
      f32x4 s = __builtin_amdgcn_mfma_f32_16x16x32_bf16(qf[0], k0, zf, 0, 0, 0);
      s = __builtin_amdgcn_mfma_f32_16x16x32_bf16(qf[1], k1, s, 0, 0, 0);
      float e0 = EXP2(s[0]), e1 = EXP2(s[1]), e2 = EXP2(s[2]), e3 = EXP2(s[3]);
      rs[0] += e0; rs[1] += e1; rs[2] += e2; rs[3] += e3;
      int p = __builtin_amdgcn_cvt_pk_fp8_f32(e0, e1, 0, false);
      p = __builtin_amdgcn_cvt_pk_fp8_f32(e2, e3, p, true);
      Ps[w][jt][ni][lane ^ (ni << 4)] = (unsigned)p;
    }
  }
  // reduce row sums across the 16 lanes sharing g (cols live in lane&15)
  float rinv[4];
#pragma unroll
  for (int r = 0; r < 4; ++r) {
    float v = rs[r];
    v += __shfl_xor(v, 1);
    v += __shfl_xor(v, 2);
    v += __shfl_xor(v, 4);
    v += __shfl_xor(v, 8);
    rinv[r] = 0x1p120f / v;               // fold 2^120 decode scale
  }
  // broadcast the wave's 16 row-scales into every lane (one-time, 16 shfl)
  float rv[16];
#pragma unroll
  for (int t = 0; t < 16; ++t)
    rv[t] = __shfl(rinv[t & 3], (t >> 2) << 4);

  // ---- pass 2: lane L owns col j=jt*64+L; int-decode, no shfl/barrier ----
  const int myni = lane >> 4, myc = lane & 15;
#pragma unroll 2
  for (int jt = 0; jt < 16; ++jt) {
    unsigned e[4];
#pragma unroll
    for (int gg = 0; gg < 4; ++gg)
      e[gg] = Ps[w][jt][myni][(gg * 16 + myc) ^ (myni << 4)];
    float cs = 0.f;
#pragma unroll
    for (int gg = 0; gg < 4; ++gg) {
#pragma unroll
      for (int r = 0; r < 4; ++r) {
        unsigned bits = ((e[gg] >> (8 * r)) & 0xffu) << 20;  // e4m3 -> f32*2^-120
        cs = fmaf(__uint_as_float(bits), rv[gg * 4 + r], cs);
      }
    }
    atomicAdd(wsum + (size_t)bh * 1024 + jt * 64 + lane, cs);
  }
#undef STAGEK
#undef KFRAG
}

// ---------------------------------------------------------------------------
// Kernel F: out[bh][d] = LN_d( (1/N) * sum_j w[bh][j] * V[bh][j][d] )
// ---------------------------------------------------------------------------
__global__ __launch_bounds__(256) void k_final(const float* __restrict__ wsum,
                                               const bf16* __restrict__ v,
                                               const float* __restrict__ gamma,
                                               const float* __restrict__ beta,
                                               float* __restrict__ out) {
  const int bh = blockIdx.x;
  const int tid = threadIdx.x;
  const int d = tid & 63, part = tid >> 6;
  const bf16* vb = v + (size_t)bh * 65536;
  const float* wb = wsum + (size_t)bh * 1024;
  float acc = 0.f;
  for (int j = part * 256; j < part * 256 + 256; ++j)
    acc += wb[j] * (float)vb[(size_t)j * 64 + d];
  __shared__ float red[4][64];
  red[part][d] = acc;
  __syncthreads();
  if (tid < 64) {
    float y = (red[0][d] + red[1][d] + red[2][d] + red[3][d]) * (1.0f / 1024.0f);
    float s1 = y;
#pragma unroll
    for (int off = 1; off < 64; off <<= 1) s1 += __shfl_xor(s1, off);
    float mu = s1 * (1.0f / 64.0f);
    float dy = y - mu;
    float s2 = dy * dy;
#pragma unroll
    for (int off = 1; off < 64; off <<= 1) s2 += __shfl_xor(s2, off);
    float rstd = rsqrtf(s2 * (1.0f / 64.0f) + 1e-5f);
    out[(size_t)bh * 64 + d] = dy * rstd * gamma[d] + beta[d];
  }
}

// ---------------------------------------------------------------------------
extern "C" void kernel_launch(void* const* d_in, const int* in_sizes, int n_in,
                              void* d_out, int out_size, void* d_ws, size_t ws_size,
                              hipStream_t stream) {
  const float* x     = (const float*)d_in[0];
  const float* Wq    = (const float*)d_in[1];
  const float* Wk    = (const float*)d_in[2];
  const float* Wv    = (const float*)d_in[3];
  const float* gamma = (const float*)d_in[4];
  const float* beta  = (const float*)d_in[5];
  float* out = (float*)d_out;

  char* ws = (char*)d_ws;
  bf16*  tbf  = (bf16*)ws;                    // 32768*640*2      = 41,943,040 B
  bf16*  wbf  = (bf16*)(ws + 41943040);       // 3072*640*2       =  3,932,160 B
  bf16*  qkv  = (bf16*)(ws + 45875200);       // 3*512*1024*64*2  = 201,326,592 B
  float* wsum = (float*)(ws + 247201792);     // 512*1024*4       =  2,097,152 B

  (void)hipMemsetAsync(wsum, 0, (size_t)512 * 1024 * sizeof(float), stream);
  k_transpose<<<dim3(16, 10, 32), 256, 0, stream>>>(x, tbf);
  k_castw3<<<7680, 256, 0, stream>>>(Wq, Wk, Wv, wbf);
  k_gemm_qkv<<<dim3(256, 24), 256, 0, stream>>>(tbf, wbf, qkv);
  k_attn<<<8192, 256, 0, stream>>>(qkv, qkv + 33554432, wsum);
  k_final<<<512, 256, 0, stream>>>(wsum, qkv + 67108864, gamma, beta, out);
}

// Round 7
// 494.177 us; speedup vs baseline: 2.4039x; 1.2846x over previous
//
#include <hip/hip_runtime.h>
#include <hip/hip_bf16.h>

typedef __bf16 bf16;
typedef __bf16 bf16x8 __attribute__((ext_vector_type(8)));
typedef float f32x4 __attribute__((ext_vector_type(4)));

#define QSCALE 0.18033688011112042f  /* (1/8) * log2(e) : folds softmax scale into Wq */

// raw v_exp_f32 (exp2). Inputs here are |x| <~ 2.5 so no edge-case handling needed.
#define EXP2(x) __builtin_amdgcn_exp2f(x)

// ---- async global->LDS (16B per lane, wave-uniform LDS base + lane*16) ----
__device__ __forceinline__ void load_lds16(const void* gp, void* lp) {
  __builtin_amdgcn_global_load_lds((const __attribute__((address_space(1))) void*)gp,
                                   (__attribute__((address_space(3))) void*)lp, 16, 0, 0);
}

// ---------------------------------------------------------------------------
// Kernel T: x [B,C,N] fp32 -> t [B,N,C] bf16   (B=32, C=640, N=1024)
// ---------------------------------------------------------------------------
__global__ __launch_bounds__(256) void k_transpose(const float* __restrict__ x,
                                                   bf16* __restrict__ t) {
  __shared__ float tile[64][65];
  const int b = blockIdx.z, c0 = blockIdx.y * 64, n0 = blockIdx.x * 64;
  const int tid = threadIdx.x, lx = tid & 63, ly = tid >> 6;
  const float* xp = x + ((size_t)b * 640 + c0) * 1024 + n0;
#pragma unroll
  for (int i = 0; i < 16; ++i) {
    int c = i * 4 + ly;
    tile[c][lx] = xp[(size_t)c * 1024 + lx];
  }
  __syncthreads();
  bf16* tp = t + ((size_t)b * 1024 + n0) * 640 + c0;
#pragma unroll
  for (int i = 0; i < 16; ++i) {
    int n = i * 4 + ly;
    tp[(size_t)n * 640 + lx] = (bf16)tile[lx][n];
  }
}

// ---------------------------------------------------------------------------
// Kernel Wc: cast all three weight matrices fp32 -> bf16 (Wq pre-scaled)
// ---------------------------------------------------------------------------
__global__ __launch_bounds__(256) void k_castw3(const float* __restrict__ wq,
                                                const float* __restrict__ wk,
                                                const float* __restrict__ wv,
                                                bf16* __restrict__ dst) {
  int i = blockIdx.x * 256 + threadIdx.x;
  if (i < 655360) dst[i] = (bf16)(wq[i] * QSCALE);
  else if (i < 1310720) dst[i] = (bf16)wk[i - 655360];
  else if (i < 1966080) dst[i] = (bf16)wv[i - 1310720];
}

// ---------------------------------------------------------------------------
// Kernel P: C[32768 x 3072] = A[32768 x 640] * B[3072 x 640]^T  (bf16 in/out)
// 128x128 tile, BK=64, 4 waves (2x2), 16x16x32 MFMA.
// R12: grid remap. Old grid(256,24) m-fastest => each of 24 n-sweeps re-read
// all 41 MB of A (~1 GB A traffic, >L2) -> GEMM was HBM-bound on A (~550 TF).
// New 1-D XCD-clustered decode: xcd = idx&7; within an XCD, n-tile is the
// fast axis so the 24 blocks sharing one A-tile run back-to-back on the SAME
// XCD (A fetched once, 41 MB total); B (3.9 MB) stays L2-hot per XCD.
// Concurrent working set ~3 A-tiles + B ~ 4.4 MB ~ per-XCD L2.
// ---------------------------------------------------------------------------
__global__ __launch_bounds__(256) void k_gemm_qkv(const bf16* __restrict__ A,
                                                  const bf16* __restrict__ Bw,
                                                  bf16* __restrict__ qkv) {
  __shared__ __align__(16) bf16 smem[2][2][8192];   // [buf][A/B][128*64] = 64 KB
  const int tid = threadIdx.x;
  const int lane = tid & 63;
  const int w = tid >> 6;
  const int wm = w & 1, wn = w >> 1;
  const int g = lane >> 4, ln = lane & 15;
  // XCD-clustered block decode: n fast within XCD, m striped across XCDs.
  const int idx = blockIdx.x;            // 0..6143
  const int xcd = idx & 7;
  const int lin = idx >> 3;              // 0..767
  const int nt = lin % 24;
  const int mt = (lin / 24) * 8 + xcd;   // 0..255
  const int m0 = mt * 128;
  const int n0 = nt * 128;

  f32x4 acc[4][4];
#pragma unroll
  for (int i = 0; i < 4; ++i)
#pragma unroll
    for (int j = 0; j < 4; ++j)
#pragma unroll
      for (int r = 0; r < 4; ++r) acc[i][j][r] = 0.f;

  // stage A+B K-tile kt into smem[buf]: chunk c holds (m=c>>3, kq=(c&7)^(m&7))
#define GSTAGE(buf, kt)                                                        \
  do {                                                                         \
    _Pragma("unroll") for (int it_ = 0; it_ < 4; ++it_) {                      \
      int c_ = it_ * 256 + w * 64 + lane;                                      \
      int m_ = c_ >> 3;                                                        \
      int kq_ = (c_ & 7) ^ (m_ & 7);                                           \
      load_lds16(A + (size_t)(m0 + m_) * 640 + ((kt) * 64 + kq_ * 8),          \
                 &smem[buf][0][(size_t)(it_ * 256 + w * 64) * 8]);             \
      load_lds16(Bw + (size_t)(n0 + m_) * 640 + ((kt) * 64 + kq_ * 8),        \
                 &smem[buf][1][(size_t)(it_ * 256 + w * 64) * 8]);             \
    }                                                                          \
  } while (0)

  GSTAGE(0, 0);
  for (int kt = 0; kt < 10; ++kt) {
    const int cur = kt & 1;
    __syncthreads();                    // drains stage(kt); buffer handoff
    if (kt + 1 < 10) GSTAGE(1 - cur, kt + 1);
    const bf16* As = smem[cur][0];
    const bf16* Bs = smem[cur][1];
#pragma unroll
    for (int kk = 0; kk < 2; ++kk) {
      bf16x8 af[4], bfr[4];
#pragma unroll
      for (int mi = 0; mi < 4; ++mi) {
        int m = wm * 64 + mi * 16 + ln;
        int cc = m * 8 + ((kk * 4 + g) ^ (m & 7));
        af[mi] = *(const bf16x8*)(As + cc * 8);
      }
#pragma unroll
      for (int ni = 0; ni < 4; ++ni) {
        int n = wn * 64 + ni * 16 + ln;
        int cc = n * 8 + ((kk * 4 + g) ^ (n & 7));
        bfr[ni] = *(const bf16x8*)(Bs + cc * 8);
      }
#pragma unroll
      for (int mi = 0; mi < 4; ++mi)
#pragma unroll
        for (int ni = 0; ni < 4; ++ni)
          acc[mi][ni] = __builtin_amdgcn_mfma_f32_16x16x32_bf16(af[mi], bfr[ni], acc[mi][ni], 0, 0, 0);
    }
  }
#undef GSTAGE

  // ---- epilogue: transpose through LDS, then 16 B stores ----
  __syncthreads();                       // all compute done; smem reusable
  bf16* ct = &smem[0][0][0];             // 32768 bf16 avail; stride 136 (pad)
#pragma unroll
  for (int mi = 0; mi < 4; ++mi)
#pragma unroll
    for (int ni = 0; ni < 4; ++ni)
#pragma unroll
      for (int r = 0; r < 4; ++r) {
        int row = wm * 64 + mi * 16 + g * 4 + r;
        int col = wn * 64 + ni * 16 + ln;
        ct[row * 136 + col] = (bf16)acc[mi][ni][r];
      }
  __syncthreads();
  const int which = n0 >> 10;
  const int hbase = (n0 >> 6) & 15;
#pragma unroll
  for (int p = 0; p < 8; ++p) {
    int row = p * 16 + (tid >> 4);       // tile row 0..127
    int chunk = tid & 15;                // 16 chunks of 8 cols
    bf16x8 vv = *(const bf16x8*)(ct + row * 136 + chunk * 8);
    int gr = m0 + row;
    int bb = gr >> 10, n = gr & 1023;
    int h = hbase + (chunk >> 3);
    int d0 = (chunk & 7) * 8;
    *(bf16x8*)(qkv + (size_t)which * 33554432 +
               (((size_t)bb * 16 + h) * 1024 + n) * 64 + d0) = vv;
  }
}

// ---------------------------------------------------------------------------
// Kernel A: fused two-pass attention column-weights (PROVEN 212us baseline).
// R12: reverted from the fp8-cache experiments (R8-R11). The cache idea is
// numerically free but every variant's LDS/VGPR footprint capped occupancy
// at 2 waves/SIMD -> latency-bound 350-920us, all slower than this 2-pass
// shape at full occupancy (busy 67%). Keeping the known-good kernel.
// grid 2048 1-D with XCD swizzle (4 i-tiles of a bh share idx%8 -> K L2-hot).
// Pass 1: l_i = sum_j exp2(s_ij)  (q pre-scaled by scale*log2e)
// Pass 2: w_j += sum_i exp2(s_ij) / l_i   via atomicAdd.
// ---------------------------------------------------------------------------
__global__ __launch_bounds__(256) void k_attn(const bf16* __restrict__ q,
                                              const bf16* __restrict__ kmat,
                                              float* __restrict__ wsum) {
  __shared__ __align__(16) bf16 Ks[2][4096];   // 2 x 64x64 bf16 = 16 KB
  const int idx = blockIdx.x;
  const int xcd = idx & 7;
  const int y = idx >> 3;
  const int it = y & 3;
  const int bh = xcd + ((y >> 2) << 3);   // 4 i-tiles of bh share idx%8
  const int tid = threadIdx.x;
  const int lane = tid & 63;
  const int w = tid >> 6;
  const int g = lane >> 4, ln = lane & 15;
  const bf16* qb = q + (size_t)bh * 65536;
  const bf16* kb = kmat + (size_t)bh * 65536;
  const int i0 = it * 256 + w * 64;

  const f32x4 zf = {0.f, 0.f, 0.f, 0.f};

#define STAGEK(buf, jt)                                                       \
  do {                                                                        \
    _Pragma("unroll") for (int call_ = 0; call_ < 2; ++call_) {               \
      int p_ = w * 128 + call_ * 64 + lane;                                   \
      int j_ = p_ >> 3;                                                       \
      int kq_ = (p_ & 7) ^ (j_ & 7);                                          \
      load_lds16(kb + (size_t)((jt) * 64 + j_) * 64 + kq_ * 8,                \
                 &Ks[buf][(size_t)(w * 128 + call_ * 64) * 8]);               \
    }                                                                         \
  } while (0)

#define KFRAG(buf, ni, kc)                                                    \
  (*(const bf16x8*)(&Ks[buf][(size_t)(((ni) * 16 + ln) * 8 +                  \
                                      (((kc) * 4 + g) ^ (ln & 7))) * 8]))

  // Q fragments: A-layout m=lane&15, k=(lane>>4)*8+j ; held in regs for both passes
  bf16x8 qf[4][2];
#pragma unroll
  for (int mi = 0; mi < 4; ++mi)
#pragma unroll
    for (int kc = 0; kc < 2; ++kc)
      qf[mi][kc] = *(const bf16x8*)(qb + (size_t)(i0 + mi * 16 + ln) * 64 + kc * 32 + g * 8);

  float rs[4][4];
#pragma unroll
  for (int mi = 0; mi < 4; ++mi)
#pragma unroll
    for (int r = 0; r < 4; ++r) rs[mi][r] = 0.f;

  // ---- pass 1: row sums ----
  STAGEK(0, 0);
  for (int jt = 0; jt < 16; ++jt) {
    const int cur = jt & 1;
    __syncthreads();                      // drains stage(jt); buffer handoff
    if (jt + 1 < 16) STAGEK(1 - cur, jt + 1);
    bf16x8 kf[4][2];
#pragma unroll
    for (int ni = 0; ni < 4; ++ni)
#pragma unroll
      for (int kc = 0; kc < 2; ++kc) kf[ni][kc] = KFRAG(cur, ni, kc);
#pragma unroll
    for (int mi = 0; mi < 4; ++mi)
#pragma unroll
      for (int ni = 0; ni < 4; ++ni) {
        f32x4 s = __builtin_amdgcn_mfma_f32_16x16x32_bf16(qf[mi][0], kf[ni][0], zf, 0, 0, 0);
        s = __builtin_amdgcn_mfma_f32_16x16x32_bf16(qf[mi][1], kf[ni][1], s, 0, 0, 0);
#pragma unroll
        for (int r = 0; r < 4; ++r) rs[mi][r] += EXP2(s[r]);
      }
  }
  // reduce row sums across the 16 lanes sharing g (cols live in lane&15)
  float rinv[4][4];
#pragma unroll
  for (int mi = 0; mi < 4; ++mi)
#pragma unroll
    for (int r = 0; r < 4; ++r) {
      float v = rs[mi][r];
      v += __shfl_xor(v, 1);
      v += __shfl_xor(v, 2);
      v += __shfl_xor(v, 4);
      v += __shfl_xor(v, 8);
      rinv[mi][r] = 1.0f / v;
    }

  // ---- pass 2: column sums scaled by 1/l_i ----
  STAGEK(0, 0);
  for (int jt = 0; jt < 16; ++jt) {
    const int cur = jt & 1;
    __syncthreads();
    if (jt + 1 < 16) STAGEK(1 - cur, jt + 1);
    bf16x8 kf[4][2];
#pragma unroll
    for (int ni = 0; ni < 4; ++ni)
#pragma unroll
      for (int kc = 0; kc < 2; ++kc) kf[ni][kc] = KFRAG(cur, ni, kc);
    float cs[4] = {0.f, 0.f, 0.f, 0.f};
#pragma unroll
    for (int mi = 0; mi < 4; ++mi)
#pragma unroll
      for (int ni = 0; ni < 4; ++ni) {
        f32x4 s = __builtin_amdgcn_mfma_f32_16x16x32_bf16(qf[mi][0], kf[ni][0], zf, 0, 0, 0);
        s = __builtin_amdgcn_mfma_f32_16x16x32_bf16(qf[mi][1], kf[ni][1], s, 0, 0, 0);
#pragma unroll
        for (int r = 0; r < 4; ++r) cs[ni] += EXP2(s[r]) * rinv[mi][r];
      }
#pragma unroll
    for (int ni = 0; ni < 4; ++ni) {
      float v = cs[ni];
      v += __shfl_xor(v, 16);
      v += __shfl_xor(v, 32);
      if (g == 0) atomicAdd(wsum + (size_t)bh * 1024 + jt * 64 + ni * 16 + ln, v);
    }
  }
#undef STAGEK
#undef KFRAG
}

// ---------------------------------------------------------------------------
// Kernel F: out[bh][d] = LN_d( (1/N) * sum_j w[bh][j] * V[bh][j][d] )
// ---------------------------------------------------------------------------
__global__ __launch_bounds__(256) void k_final(const float* __restrict__ wsum,
                                               const bf16* __restrict__ v,
                                               const float* __restrict__ gamma,
                                               const float* __restrict__ beta,
                                               float* __restrict__ out) {
  const int bh = blockIdx.x;
  const int tid = threadIdx.x;
  const int d = tid & 63, part = tid >> 6;
  const bf16* vb = v + (size_t)bh * 65536;
  const float* wb = wsum + (size_t)bh * 1024;
  float acc = 0.f;
  for (int j = part * 256; j < part * 256 + 256; ++j)
    acc += wb[j] * (float)vb[(size_t)j * 64 + d];
  __shared__ float red[4][64];
  red[part][d] = acc;
  __syncthreads();
  if (tid < 64) {
    float y = (red[0][d] + red[1][d] + red[2][d] + red[3][d]) * (1.0f / 1024.0f);
    float s1 = y;
#pragma unroll
    for (int off = 1; off < 64; off <<= 1) s1 += __shfl_xor(s1, off);
    float mu = s1 * (1.0f / 64.0f);
    float dy = y - mu;
    float s2 = dy * dy;
#pragma unroll
    for (int off = 1; off < 64; off <<= 1) s2 += __shfl_xor(s2, off);
    float rstd = rsqrtf(s2 * (1.0f / 64.0f) + 1e-5f);
    out[(size_t)bh * 64 + d] = dy * rstd * gamma[d] + beta[d];
  }
}

// ---------------------------------------------------------------------------
extern "C" void kernel_launch(void* const* d_in, const int* in_sizes, int n_in,
                              void* d_out, int out_size, void* d_ws, size_t ws_size,
                              hipStream_t stream) {
  const float* x     = (const float*)d_in[0];
  const float* Wq    = (const float*)d_in[1];
  const float* Wk    = (const float*)d_in[2];
  const float* Wv    = (const float*)d_in[3];
  const float* gamma = (const float*)d_in[4];
  const float* beta  = (const float*)d_in[5];
  float* out = (float*)d_out;

  char* ws = (char*)d_ws;
  bf16*  tbf  = (bf16*)ws;                    // 32768*640*2      = 41,943,040 B
  bf16*  wbf  = (bf16*)(ws + 41943040);       // 3072*640*2       =  3,932,160 B
  bf16*  qkv  = (bf16*)(ws + 45875200);       // 3*512*1024*64*2  = 201,326,592 B
  float* wsum = (float*)(ws + 247201792);     // 512*1024*4       =  2,097,152 B

  (void)hipMemsetAsync(wsum, 0, (size_t)512 * 1024 * sizeof(float), stream);
  k_transpose<<<dim3(16, 10, 32), 256, 0, stream>>>(x, tbf);
  k_castw3<<<7680, 256, 0, stream>>>(Wq, Wk, Wv, wbf);
  k_gemm_qkv<<<6144, 256, 0, stream>>>(tbf, wbf, qkv);
  k_attn<<<2048, 256, 0, stream>>>(qkv, qkv + 33554432, wsum);
  k_final<<<512, 256, 0, stream>>>(wsum, qkv + 67108864, gamma, beta, out);
}